// Round 6
// baseline (1608.605 us; speedup 1.0000x reference)
//
#include <hip/hip_runtime.h>

typedef unsigned short u16;
typedef _Float16 f16;
typedef _Float16 f16x2 __attribute__((ext_vector_type(2)));
typedef _Float16 f16x8 __attribute__((ext_vector_type(8)));
typedef float f32x4 __attribute__((ext_vector_type(4)));

#define AS1 __attribute__((address_space(1)))
#define AS3 __attribute__((address_space(3)))

constexpr int N_NODES = 8000;
constexpr int N_EDGES = 64000;
constexpr int F_IN    = 2560;   // in channels (== H*C, both layers)
constexpr int HEADS   = 8;
constexpr int CPH     = 320;    // channels per head
constexpr int HC      = 2560;   // HEADS*CPH
constexpr int NW      = 5120;   // fused GEMM output width (XL | XR)
constexpr int NGRAPH  = 16;
constexpr float SLOPE = 0.2f;
constexpr int MT      = 42;     // ceil(8000/192) m-tiles

// ---------------- f32 -> f16 bulk convert (n divisible by 1024) ----------------
__global__ __launch_bounds__(256)
void cvt_f32_f16(const float* __restrict__ in, f16* __restrict__ out, int n)
{
  const int i = (blockIdx.x * 256 + threadIdx.x) * 4;
  if (i >= n) return;
  const float4 v = *(const float4*)(in + i);
  f16 o[4] = {(f16)v.x, (f16)v.y, (f16)v.z, (f16)v.w};
  *(ushort4*)(out + i) = *(const ushort4*)o;
}

// ------ weight transpose + convert: in f32 [R=2560][C=2560] -> out f16 [C][R] ------
__global__ __launch_bounds__(256)
void transpose_w(const float* __restrict__ in, f16* __restrict__ out)
{
  __shared__ u16 tile[64][66];     // +2 pad to break bank stride
  const int bx = blockIdx.x * 64;  // col tile (input)
  const int by = blockIdx.y * 64;  // row tile (input)
  const int tx = threadIdx.x & 63;
  const int ty = threadIdx.x >> 6;
  #pragma unroll
  for (int i = ty; i < 64; i += 4) {
    f16 h = (f16)in[(size_t)(by + i) * HC + bx + tx];
    u16 u; __builtin_memcpy(&u, &h, 2);
    tile[i][tx] = u;
  }
  __syncthreads();
  #pragma unroll
  for (int i = ty; i < 64; i += 4) {
    u16 u = tile[tx][i];
    f16 h; __builtin_memcpy(&h, &u, 2);
    out[(size_t)(bx + i) * F_IN + by + tx] = h;
  }
}

// ---- Fused GEMM: [XL|XR][M,5120](f16) = A[M,K](f16) @ BT[5120,K]^T + bias; fp32 acc ----
// 192x128 block tile, BK=32, 256 threads / 4 waves (2x2), each wave 96x64 (24 MFMA/K-step).
// reads/MFMA = 10/24 (vs 8/16 at 64x64) -> LDS pipe no longer dominant.
// LDS k-chunk XOR swizzle (phys = logical ^ ((row>>1)&3)) keeps ds_read_b128 conflict-free.
__global__ __launch_bounds__(256)
void gemm_fused(const f16* __restrict__ A, const f16* __restrict__ BT,
                const float* __restrict__ bl, const float* __restrict__ br,
                f16* __restrict__ XL, f16* __restrict__ XR, int M)
{
  __shared__ __align__(16) f16 sA[192 * 32];   // 12 KB
  __shared__ __align__(16) f16 sB[128 * 32];   // 8 KB
  const int t    = threadIdx.x;     // 0..255
  const int lane = t & 63;
  const int wave = t >> 6;          // 0..3
  // m-fastest order: consecutive blocks share one B-tile (L2-resident)
  const int mt = blockIdx.x % MT;
  const int nt = blockIdx.x / MT;
  const int m0 = mt * 192;
  const int n0 = nt * 128;
  const int fm = (wave >> 1) * 96;  // 0,96
  const int fn = (wave & 1) * 64;   // 0,64
  const int ml = lane & 15;
  const int lq = lane >> 4;         // logical k-chunk 0..3

  f32x4 acc[6][4] = {};

  for (int k0 = 0; k0 < F_IN; k0 += 32) {
    __syncthreads();
    // stage A: 768 chunk-slots (192 rows x 4 chunks of 8 f16), 3 per thread
    #pragma unroll
    for (int j = 0; j < 3; ++j) {
      const int s = j * 256 + t;
      const int r = s >> 2;
      const int lc = (s & 3) ^ ((r >> 1) & 3);   // logical chunk for this phys slot
      int ra = m0 + r; ra = (ra < M) ? ra : (M - 1);
      const f16* ga = A + (size_t)ra * F_IN + k0 + lc * 8;
      __builtin_amdgcn_global_load_lds((AS1 const void*)ga,
                                       (AS3 void*)(sA + s * 8), 16, 0, 0);
    }
    // stage B: 512 chunk-slots (128 rows x 4 chunks), 2 per thread
    #pragma unroll
    for (int j = 0; j < 2; ++j) {
      const int s = j * 256 + t;
      const int r = s >> 2;
      const int lc = (s & 3) ^ ((r >> 1) & 3);
      const f16* gb = BT + (size_t)(n0 + r) * F_IN + k0 + lc * 8;
      __builtin_amdgcn_global_load_lds((AS1 const void*)gb,
                                       (AS3 void*)(sB + s * 8), 16, 0, 0);
    }
    __syncthreads();

    f16x8 af[6], bfr[4];
    #pragma unroll
    for (int i = 0; i < 6; ++i) {
      const int row = fm + i * 16 + ml;
      const int p = lq ^ ((row >> 1) & 3);
      af[i] = *(const f16x8*)(sA + (row * 4 + p) * 8);
    }
    #pragma unroll
    for (int j = 0; j < 4; ++j) {
      const int row = fn + j * 16 + ml;
      const int p = lq ^ ((row >> 1) & 3);
      bfr[j] = *(const f16x8*)(sB + (row * 4 + p) * 8);
    }

    #pragma unroll
    for (int i = 0; i < 6; ++i)
      #pragma unroll
      for (int j = 0; j < 4; ++j)
        acc[i][j] = __builtin_amdgcn_mfma_f32_16x16x32_f16(af[i], bfr[j], acc[i][j], 0, 0, 0);
  }

  // epilogue: n0 block (128 wide) lies entirely in XL (n0<2560) or XR
  const bool left = (n0 < HC);
  f16* __restrict__ OUT = left ? XL : XR;
  const float* __restrict__ bias = left ? bl : br;
  const int nb = left ? n0 : (n0 - HC);
  const int rg = (lane >> 4) * 4;
  #pragma unroll
  for (int j = 0; j < 4; ++j) {
    const int gn = nb + fn + j * 16 + ml;
    const float bv = bias[gn];
    #pragma unroll
    for (int i = 0; i < 6; ++i) {
      #pragma unroll
      for (int r = 0; r < 4; ++r) {
        const int gm = m0 + fm + i * 16 + rg + r;
        if (gm < M) OUT[(size_t)gm * HC + gn] = (f16)(acc[i][j][r] + bv);
      }
    }
  }
}

// ---------------- CSR build ----------------
__global__ __launch_bounds__(256)
void count_edges(const int* __restrict__ dst, int* __restrict__ counts)
{
  const int e = blockIdx.x * 256 + threadIdx.x;
  if (e < N_EDGES) atomicAdd(&counts[dst[e]], 1);
}

__global__ __launch_bounds__(256)
void scan_offsets(const int* __restrict__ counts, int* __restrict__ offs, int* __restrict__ cur)
{
  __shared__ int wtot[4];
  const int t = threadIdx.x;
  const int lane = t & 63, wave = t >> 6;
  const int base = t * 32;
  int loc[32];
  int run = 0;
  #pragma unroll
  for (int i = 0; i < 32; ++i) {
    const int idx = base + i;
    const int v = (idx < N_NODES) ? counts[idx] : 0;
    loc[i] = run;
    run += v;
  }
  int incl = run;
  #pragma unroll
  for (int off = 1; off < 64; off <<= 1) {
    int y = __shfl_up(incl, off, 64);
    if (lane >= off) incl += y;
  }
  const int excl = incl - run;
  if (lane == 63) wtot[wave] = incl;
  __syncthreads();
  int wb = 0;
  for (int wv = 0; wv < wave; ++wv) wb += wtot[wv];
  const int mybase = wb + excl;
  #pragma unroll
  for (int i = 0; i < 32; ++i) {
    const int idx = base + i;
    if (idx < N_NODES) { offs[idx] = mybase + loc[i]; cur[idx] = mybase + loc[i]; }
  }
  if (t == 255) offs[N_NODES] = wb + incl;
}

__global__ __launch_bounds__(256)
void fill_csr(const int* __restrict__ dst, int* __restrict__ cur, int* __restrict__ eids)
{
  const int e = blockIdx.x * 256 + threadIdx.x;
  if (e < N_EDGES) {
    const int p = atomicAdd(&cur[dst[e]], 1);
    eids[p] = e;
  }
}

// ---- Fused edge phase: scores + online segment-softmax + aggregation, one pass ----
// One block per node; wave w handles heads 2w (lanes 0-31) and 2w+1 (lanes 32-63).
// Lane l32 of head h owns channel PAIRS c = h*320 + 2*l32 + 64k (k=0..4) -> dword loads.
__global__ __launch_bounds__(256)
void gat_edge_fused(const f16* __restrict__ XL, const f16* __restrict__ XR,
                    const float* __restrict__ We, const float* __restrict__ att,
                    const float* __restrict__ eattr,
                    const int* __restrict__ src,
                    const int* __restrict__ offs, const int* __restrict__ eids,
                    const float* __restrict__ bias,
                    f16* __restrict__ out)
{
  const int n    = blockIdx.x;
  const int t    = threadIdx.x;
  const int wave = t >> 6;
  const int lane = t & 63;
  const int half = lane >> 5;
  const int l32  = lane & 31;
  const int h    = wave * 2 + half;
  const int cb   = h * CPH + 2 * l32;   // + 64*k

  float2 xr[5], wv[5], av[5];
  #pragma unroll
  for (int k = 0; k < 5; ++k) {
    const int c = cb + 64 * k;
    const f16x2 p = *(const f16x2*)(XR + (size_t)n * HC + c);
    xr[k] = make_float2((float)p.x, (float)p.y);
    wv[k] = *(const float2*)(We + c);
    av[k] = *(const float2*)(att + c);
  }

  float m = -3.0e38f, l = 0.f;
  float acc0[5], acc1[5];
  #pragma unroll
  for (int k = 0; k < 5; ++k) { acc0[k] = 0.f; acc1[k] = 0.f; }

  const int b = offs[n], e = offs[n + 1];
  for (int p = b; p < e; ++p) {
    const int eid  = eids[p];
    const int s    = src[eid];
    const float ea = eattr[eid];
    const f16* row = XL + (size_t)s * HC;
    float xl0[5], xl1[5];
    float partial = 0.f;
    #pragma unroll
    for (int k = 0; k < 5; ++k) {
      const f16x2 q = *(const f16x2*)(row + cb + 64 * k);
      xl0[k] = (float)q.x;
      xl1[k] = (float)q.y;
      float v0 = xl0[k] + xr[k].x + ea * wv[k].x;
      float v1 = xl1[k] + xr[k].y + ea * wv[k].y;
      v0 = (v0 > 0.f) ? v0 : SLOPE * v0;
      v1 = (v1 > 0.f) ? v1 : SLOPE * v1;
      partial += v0 * av[k].x + v1 * av[k].y;
    }
    // reduce across the 32-lane half (masks < 32 keep halves closed)
    #pragma unroll
    for (int msk = 16; msk >= 1; msk >>= 1)
      partial += __shfl_xor(partial, msk, 64);
    const float sc    = partial;
    const float mn    = fmaxf(m, sc);
    const float scale = __expf(m - mn);
    const float w     = __expf(sc - mn);
    l = l * scale + w;
    #pragma unroll
    for (int k = 0; k < 5; ++k) {
      acc0[k] = acc0[k] * scale + w * xl0[k];
      acc1[k] = acc1[k] * scale + w * xl1[k];
    }
    m = mn;
  }

  const float inv = (l > 0.f) ? 1.f / l : 0.f;   // deg-0 node -> out = bias (matches ref)
  #pragma unroll
  for (int k = 0; k < 5; ++k) {
    const int c = cb + 64 * k;
    f16x2 o;
    o.x = (f16)(acc0[k] * inv + bias[c]);
    o.y = (f16)(acc1[k] * inv + bias[c + 1]);
    *(f16x2*)(out + (size_t)n * HC + c) = o;
  }
}

// ---------------- global mean pool (batch is sorted), f16 in, f32 out ----------------
__global__ __launch_bounds__(256)
void pool_kernel(const f16* __restrict__ Hm, const int* __restrict__ batch, float* __restrict__ out)
{
  __shared__ int se[2];
  const int g = blockIdx.x;
  const int chunk = blockIdx.y;
  const int t = threadIdx.x;
  if (t < 2) {
    const int target = g + t;
    int lo = 0, hi = N_NODES;
    while (lo < hi) { const int mid = (lo + hi) >> 1; if (batch[mid] < target) lo = mid + 1; else hi = mid; }
    se[t] = lo;
  }
  __syncthreads();
  const int s0 = se[0], s1 = se[1];
  const int c = chunk * 256 + t;
  float sum = 0.f;
  for (int n = s0; n < s1; ++n) sum += (float)Hm[(size_t)n * HC + c];
  int cnt = s1 - s0; if (cnt < 1) cnt = 1;
  out[g * HC + c] = sum / (float)cnt;
}

// ---------------- host: one GATv2 layer (A f16 -> OUT f16) ----------------
static void run_layer(const f16* A, const float* Wl, const float* bl,
                      const float* Wr, const float* br,
                      const float* We, const float* att, const float* bias,
                      const int* src, const float* eattr,
                      f16* WT, f16* XL, f16* XR,
                      const int* offs, const int* eids, f16* OUT, hipStream_t stream)
{
  dim3 tgrid(HC / 64, F_IN / 64);
  transpose_w<<<tgrid, 256, 0, stream>>>(Wl, WT);
  transpose_w<<<tgrid, 256, 0, stream>>>(Wr, WT + (size_t)HC * F_IN);
  gemm_fused<<<MT * (NW / 128), 256, 0, stream>>>(A, WT, bl, br, XL, XR, N_NODES);
  gat_edge_fused<<<N_NODES, 256, 0, stream>>>(XL, XR, We, att, eattr, src, offs, eids, bias, OUT);
}

extern "C" void kernel_launch(void* const* d_in, const int* in_sizes, int n_in,
                              void* d_out, int out_size, void* d_ws, size_t ws_size,
                              hipStream_t stream)
{
  const float* x     = (const float*)d_in[0];
  const int*   eidx  = (const int*)d_in[1];
  const float* eattr = (const float*)d_in[2];
  const int*   batch = (const int*)d_in[3];
  const float* Wl1  = (const float*)d_in[4];
  const float* bl1  = (const float*)d_in[5];
  const float* Wr1  = (const float*)d_in[6];
  const float* br1  = (const float*)d_in[7];
  const float* We1  = (const float*)d_in[8];
  const float* att1 = (const float*)d_in[9];
  const float* bias1= (const float*)d_in[10];
  const float* Wl2  = (const float*)d_in[11];
  const float* bl2  = (const float*)d_in[12];
  const float* Wr2  = (const float*)d_in[13];
  const float* br2  = (const float*)d_in[14];
  const float* We2  = (const float*)d_in[15];
  const float* att2 = (const float*)d_in[16];
  const float* bias2= (const float*)d_in[17];
  float* out = (float*)d_out;

  const int* src = eidx;
  const int* dst = eidx + N_EDGES;

  char* w = (char*)d_ws;
  auto take = [&](size_t b) { char* p = w; w += (b + 255) & ~(size_t)255; return p; };
  f16*   Xh    = (f16*)take((size_t)N_NODES * F_IN * 2);   // layer-1 A / layer-1 out (reused)
  f16*   H2h   = (f16*)take((size_t)N_NODES * HC * 2);     // layer-2 out
  f16*   WT    = (f16*)take((size_t)NW * F_IN * 2);        // fused transposed weights
  f16*   XL    = (f16*)take((size_t)N_NODES * HC * 2);
  f16*   XR    = (f16*)take((size_t)N_NODES * HC * 2);
  int*   counts= (int*)take((size_t)N_NODES * 4);
  int*   offs  = (int*)take((size_t)(N_NODES + 1) * 4);
  int*   cur   = (int*)take((size_t)N_NODES * 4);
  int*   eids  = (int*)take((size_t)N_EDGES * 4);

  hipMemsetAsync(counts, 0, N_NODES * 4, stream);
  count_edges<<<N_EDGES / 256, 256, 0, stream>>>(dst, counts);
  scan_offsets<<<1, 256, 0, stream>>>(counts, offs, cur);
  fill_csr<<<N_EDGES / 256, 256, 0, stream>>>(dst, cur, eids);

  cvt_f32_f16<<<(N_NODES * F_IN) / 1024, 256, 0, stream>>>(x, Xh, N_NODES * F_IN);

  // layer 1: Xh -> Xh (edge kernel writes after GEMM has consumed Xh; stream-ordered, safe)
  run_layer(Xh, Wl1, bl1, Wr1, br1, We1, att1, bias1, src, eattr,
            WT, XL, XR, offs, eids, Xh, stream);
  // layer 2: Xh -> H2h
  run_layer(Xh, Wl2, bl2, Wr2, br2, We2, att2, bias2, src, eattr,
            WT, XL, XR, offs, eids, H2h, stream);

  pool_kernel<<<dim3(NGRAPH, HC / 256), 256, 0, stream>>>(H2h, batch, out);
}

// Round 7
// 1212.594 us; speedup vs baseline: 1.3266x; 1.3266x over previous
//
#include <hip/hip_runtime.h>

typedef unsigned short u16;
typedef _Float16 f16;
typedef _Float16 f16x2 __attribute__((ext_vector_type(2)));
typedef _Float16 f16x8 __attribute__((ext_vector_type(8)));
typedef float f32x4 __attribute__((ext_vector_type(4)));

#define AS1 __attribute__((address_space(1)))
#define AS3 __attribute__((address_space(3)))

constexpr int N_NODES = 8000;
constexpr int N_EDGES = 64000;
constexpr int F_IN    = 2560;   // in channels (== H*C, both layers)
constexpr int HEADS   = 8;
constexpr int CPH     = 320;    // channels per head
constexpr int HC      = 2560;   // HEADS*CPH
constexpr int NW      = 5120;   // fused GEMM output width (XL | XR)
constexpr int NGRAPH  = 16;
constexpr float SLOPE = 0.2f;
constexpr int MT      = 63;     // ceil(8000/128) m-tiles

// ---------------- f32 -> f16 bulk convert (n divisible by 1024) ----------------
__global__ __launch_bounds__(256)
void cvt_f32_f16(const float* __restrict__ in, f16* __restrict__ out, int n)
{
  const int i = (blockIdx.x * 256 + threadIdx.x) * 4;
  if (i >= n) return;
  const float4 v = *(const float4*)(in + i);
  f16 o[4] = {(f16)v.x, (f16)v.y, (f16)v.z, (f16)v.w};
  *(ushort4*)(out + i) = *(const ushort4*)o;
}

// ------ weight transpose + convert: in f32 [R=2560][C=2560] -> out f16 [C][R] ------
__global__ __launch_bounds__(256)
void transpose_w(const float* __restrict__ in, f16* __restrict__ out)
{
  __shared__ u16 tile[64][66];     // +2 pad to break bank stride
  const int bx = blockIdx.x * 64;  // col tile (input)
  const int by = blockIdx.y * 64;  // row tile (input)
  const int tx = threadIdx.x & 63;
  const int ty = threadIdx.x >> 6;
  #pragma unroll
  for (int i = ty; i < 64; i += 4) {
    f16 h = (f16)in[(size_t)(by + i) * HC + bx + tx];
    u16 u; __builtin_memcpy(&u, &h, 2);
    tile[i][tx] = u;
  }
  __syncthreads();
  #pragma unroll
  for (int i = ty; i < 64; i += 4) {
    u16 u = tile[tx][i];
    f16 h; __builtin_memcpy(&h, &u, 2);
    out[(size_t)(bx + i) * F_IN + by + tx] = h;
  }
}

// ---- Fused GEMM: [XL|XR][M,5120](f16) = A[M,K](f16) @ BT[5120,K]^T + bias; fp32 acc ----
// 128x128 tile, BK=32, 256 threads / 4 waves (2x2), each wave 64x64 (16 MFMA/K-step).
// m-fastest block order (63 consecutive blocks share one B-tile) + XOR k-chunk swizzle
// (phys = logical ^ ((row>>1)&3)): R5-verified FETCH ~160MB, conflicts = 0.
// 2520 blocks, ~56 VGPR, 16KB LDS -> deep residency for barrier-latency overlap.
__global__ __launch_bounds__(256)
void gemm_fused(const f16* __restrict__ A, const f16* __restrict__ BT,
                const float* __restrict__ bl, const float* __restrict__ br,
                f16* __restrict__ XL, f16* __restrict__ XR, int M)
{
  __shared__ __align__(16) f16 sA[128 * 32];   // 8 KB
  __shared__ __align__(16) f16 sB[128 * 32];   // 8 KB
  const int t    = threadIdx.x;     // 0..255
  const int lane = t & 63;
  const int wave = t >> 6;          // 0..3
  const int mt = blockIdx.x % MT;
  const int nt = blockIdx.x / MT;
  const int m0 = mt * 128;
  const int n0 = nt * 128;
  const int fm = (wave >> 1) * 64;  // 0,64
  const int fn = (wave & 1) * 64;   // 0,64
  const int ml = lane & 15;
  const int lq = lane >> 4;         // logical k-chunk 0..3

  f32x4 acc[4][4] = {};

  for (int k0 = 0; k0 < F_IN; k0 += 32) {
    __syncthreads();
    // stage A: 512 chunk-slots (128 rows x 4 chunks of 8 f16), 2 per thread
    #pragma unroll
    for (int j = 0; j < 2; ++j) {
      const int s = j * 256 + t;
      const int r = s >> 2;
      const int lc = (s & 3) ^ ((r >> 1) & 3);   // logical chunk for this phys slot
      int ra = m0 + r; ra = (ra < M) ? ra : (M - 1);
      const f16* ga = A + (size_t)ra * F_IN + k0 + lc * 8;
      __builtin_amdgcn_global_load_lds((AS1 const void*)ga,
                                       (AS3 void*)(sA + s * 8), 16, 0, 0);
    }
    // stage B: 512 chunk-slots, 2 per thread
    #pragma unroll
    for (int j = 0; j < 2; ++j) {
      const int s = j * 256 + t;
      const int r = s >> 2;
      const int lc = (s & 3) ^ ((r >> 1) & 3);
      const f16* gb = BT + (size_t)(n0 + r) * F_IN + k0 + lc * 8;
      __builtin_amdgcn_global_load_lds((AS1 const void*)gb,
                                       (AS3 void*)(sB + s * 8), 16, 0, 0);
    }
    __syncthreads();

    f16x8 af[4], bfr[4];
    #pragma unroll
    for (int i = 0; i < 4; ++i) {
      const int row = fm + i * 16 + ml;
      const int p = lq ^ ((row >> 1) & 3);
      af[i] = *(const f16x8*)(sA + (row * 4 + p) * 8);
    }
    #pragma unroll
    for (int j = 0; j < 4; ++j) {
      const int row = fn + j * 16 + ml;
      const int p = lq ^ ((row >> 1) & 3);
      bfr[j] = *(const f16x8*)(sB + (row * 4 + p) * 8);
    }

    #pragma unroll
    for (int i = 0; i < 4; ++i)
      #pragma unroll
      for (int j = 0; j < 4; ++j)
        acc[i][j] = __builtin_amdgcn_mfma_f32_16x16x32_f16(af[i], bfr[j], acc[i][j], 0, 0, 0);
  }

  // epilogue: n0 block (128 wide) lies entirely in XL (n0<2560) or XR
  const bool left = (n0 < HC);
  f16* __restrict__ OUT = left ? XL : XR;
  const float* __restrict__ bias = left ? bl : br;
  const int nb = left ? n0 : (n0 - HC);
  const int rg = (lane >> 4) * 4;
  #pragma unroll
  for (int j = 0; j < 4; ++j) {
    const int gn = nb + fn + j * 16 + ml;
    const float bv = bias[gn];
    #pragma unroll
    for (int i = 0; i < 4; ++i) {
      #pragma unroll
      for (int r = 0; r < 4; ++r) {
        const int gm = m0 + fm + i * 16 + rg + r;
        if (gm < M) OUT[(size_t)gm * HC + gn] = (f16)(acc[i][j][r] + bv);
      }
    }
  }
}

// ---------------- CSR build ----------------
__global__ __launch_bounds__(256)
void count_edges(const int* __restrict__ dst, int* __restrict__ counts)
{
  const int e = blockIdx.x * 256 + threadIdx.x;
  if (e < N_EDGES) atomicAdd(&counts[dst[e]], 1);
}

__global__ __launch_bounds__(256)
void scan_offsets(const int* __restrict__ counts, int* __restrict__ offs, int* __restrict__ cur)
{
  __shared__ int wtot[4];
  const int t = threadIdx.x;
  const int lane = t & 63, wave = t >> 6;
  const int base = t * 32;
  int loc[32];
  int run = 0;
  #pragma unroll
  for (int i = 0; i < 32; ++i) {
    const int idx = base + i;
    const int v = (idx < N_NODES) ? counts[idx] : 0;
    loc[i] = run;
    run += v;
  }
  int incl = run;
  #pragma unroll
  for (int off = 1; off < 64; off <<= 1) {
    int y = __shfl_up(incl, off, 64);
    if (lane >= off) incl += y;
  }
  const int excl = incl - run;
  if (lane == 63) wtot[wave] = incl;
  __syncthreads();
  int wb = 0;
  for (int wv = 0; wv < wave; ++wv) wb += wtot[wv];
  const int mybase = wb + excl;
  #pragma unroll
  for (int i = 0; i < 32; ++i) {
    const int idx = base + i;
    if (idx < N_NODES) { offs[idx] = mybase + loc[i]; cur[idx] = mybase + loc[i]; }
  }
  if (t == 255) offs[N_NODES] = wb + incl;
}

__global__ __launch_bounds__(256)
void fill_csr(const int* __restrict__ dst, int* __restrict__ cur, int* __restrict__ eids)
{
  const int e = blockIdx.x * 256 + threadIdx.x;
  if (e < N_EDGES) {
    const int p = atomicAdd(&cur[dst[e]], 1);
    eids[p] = e;
  }
}

// ---- Fused edge phase: scores + online segment-softmax + aggregation, one pass ----
// One block per node; wave w handles heads 2w (lanes 0-31) and 2w+1 (lanes 32-63).
// Lane l32 of head h owns channel PAIRS c = h*320 + 2*l32 + 64k (k=0..4) -> dword loads.
__global__ __launch_bounds__(256)
void gat_edge_fused(const f16* __restrict__ XL, const f16* __restrict__ XR,
                    const float* __restrict__ We, const float* __restrict__ att,
                    const float* __restrict__ eattr,
                    const int* __restrict__ src,
                    const int* __restrict__ offs, const int* __restrict__ eids,
                    const float* __restrict__ bias,
                    f16* __restrict__ out)
{
  const int n    = blockIdx.x;
  const int t    = threadIdx.x;
  const int wave = t >> 6;
  const int lane = t & 63;
  const int half = lane >> 5;
  const int l32  = lane & 31;
  const int h    = wave * 2 + half;
  const int cb   = h * CPH + 2 * l32;   // + 64*k

  float2 xr[5], wv[5], av[5];
  #pragma unroll
  for (int k = 0; k < 5; ++k) {
    const int c = cb + 64 * k;
    const f16x2 p = *(const f16x2*)(XR + (size_t)n * HC + c);
    xr[k] = make_float2((float)p.x, (float)p.y);
    wv[k] = *(const float2*)(We + c);
    av[k] = *(const float2*)(att + c);
  }

  float m = -3.0e38f, l = 0.f;
  float acc0[5], acc1[5];
  #pragma unroll
  for (int k = 0; k < 5; ++k) { acc0[k] = 0.f; acc1[k] = 0.f; }

  const int b = offs[n], e = offs[n + 1];
  for (int p = b; p < e; ++p) {
    const int eid  = eids[p];
    const int s    = src[eid];
    const float ea = eattr[eid];
    const f16* row = XL + (size_t)s * HC;
    float xl0[5], xl1[5];
    float partial = 0.f;
    #pragma unroll
    for (int k = 0; k < 5; ++k) {
      const f16x2 q = *(const f16x2*)(row + cb + 64 * k);
      xl0[k] = (float)q.x;
      xl1[k] = (float)q.y;
      float v0 = xl0[k] + xr[k].x + ea * wv[k].x;
      float v1 = xl1[k] + xr[k].y + ea * wv[k].y;
      v0 = (v0 > 0.f) ? v0 : SLOPE * v0;
      v1 = (v1 > 0.f) ? v1 : SLOPE * v1;
      partial += v0 * av[k].x + v1 * av[k].y;
    }
    // reduce across the 32-lane half (masks < 32 keep halves closed)
    #pragma unroll
    for (int msk = 16; msk >= 1; msk >>= 1)
      partial += __shfl_xor(partial, msk, 64);
    const float sc    = partial;
    const float mn    = fmaxf(m, sc);
    const float scale = __expf(m - mn);
    const float w     = __expf(sc - mn);
    l = l * scale + w;
    #pragma unroll
    for (int k = 0; k < 5; ++k) {
      acc0[k] = acc0[k] * scale + w * xl0[k];
      acc1[k] = acc1[k] * scale + w * xl1[k];
    }
    m = mn;
  }

  const float inv = (l > 0.f) ? 1.f / l : 0.f;   // deg-0 node -> out = bias (matches ref)
  #pragma unroll
  for (int k = 0; k < 5; ++k) {
    const int c = cb + 64 * k;
    f16x2 o;
    o.x = (f16)(acc0[k] * inv + bias[c]);
    o.y = (f16)(acc1[k] * inv + bias[c + 1]);
    *(f16x2*)(out + (size_t)n * HC + c) = o;
  }
}

// ---------------- global mean pool (batch is sorted), f16 in, f32 out ----------------
__global__ __launch_bounds__(256)
void pool_kernel(const f16* __restrict__ Hm, const int* __restrict__ batch, float* __restrict__ out)
{
  __shared__ int se[2];
  const int g = blockIdx.x;
  const int chunk = blockIdx.y;
  const int t = threadIdx.x;
  if (t < 2) {
    const int target = g + t;
    int lo = 0, hi = N_NODES;
    while (lo < hi) { const int mid = (lo + hi) >> 1; if (batch[mid] < target) lo = mid + 1; else hi = mid; }
    se[t] = lo;
  }
  __syncthreads();
  const int s0 = se[0], s1 = se[1];
  const int c = chunk * 256 + t;
  float sum = 0.f;
  for (int n = s0; n < s1; ++n) sum += (float)Hm[(size_t)n * HC + c];
  int cnt = s1 - s0; if (cnt < 1) cnt = 1;
  out[g * HC + c] = sum / (float)cnt;
}

// ---------------- host: one GATv2 layer (A f16 -> OUT f16) ----------------
static void run_layer(const f16* A, const float* Wl, const float* bl,
                      const float* Wr, const float* br,
                      const float* We, const float* att, const float* bias,
                      const int* src, const float* eattr,
                      f16* WT, f16* XL, f16* XR,
                      const int* offs, const int* eids, f16* OUT, hipStream_t stream)
{
  dim3 tgrid(HC / 64, F_IN / 64);
  transpose_w<<<tgrid, 256, 0, stream>>>(Wl, WT);
  transpose_w<<<tgrid, 256, 0, stream>>>(Wr, WT + (size_t)HC * F_IN);
  gemm_fused<<<MT * (NW / 128), 256, 0, stream>>>(A, WT, bl, br, XL, XR, N_NODES);
  gat_edge_fused<<<N_NODES, 256, 0, stream>>>(XL, XR, We, att, eattr, src, offs, eids, bias, OUT);
}

extern "C" void kernel_launch(void* const* d_in, const int* in_sizes, int n_in,
                              void* d_out, int out_size, void* d_ws, size_t ws_size,
                              hipStream_t stream)
{
  const float* x     = (const float*)d_in[0];
  const int*   eidx  = (const int*)d_in[1];
  const float* eattr = (const float*)d_in[2];
  const int*   batch = (const int*)d_in[3];
  const float* Wl1  = (const float*)d_in[4];
  const float* bl1  = (const float*)d_in[5];
  const float* Wr1  = (const float*)d_in[6];
  const float* br1  = (const float*)d_in[7];
  const float* We1  = (const float*)d_in[8];
  const float* att1 = (const float*)d_in[9];
  const float* bias1= (const float*)d_in[10];
  const float* Wl2  = (const float*)d_in[11];
  const float* bl2  = (const float*)d_in[12];
  const float* Wr2  = (const float*)d_in[13];
  const float* br2  = (const float*)d_in[14];
  const float* We2  = (const float*)d_in[15];
  const float* att2 = (const float*)d_in[16];
  const float* bias2= (const float*)d_in[17];
  float* out = (float*)d_out;

  const int* src = eidx;
  const int* dst = eidx + N_EDGES;

  char* w = (char*)d_ws;
  auto take = [&](size_t b) { char* p = w; w += (b + 255) & ~(size_t)255; return p; };
  f16*   Xh    = (f16*)take((size_t)N_NODES * F_IN * 2);   // layer-1 A / layer-1 out (reused)
  f16*   H2h   = (f16*)take((size_t)N_NODES * HC * 2);     // layer-2 out
  f16*   WT    = (f16*)take((size_t)NW * F_IN * 2);        // fused transposed weights
  f16*   XL    = (f16*)take((size_t)N_NODES * HC * 2);
  f16*   XR    = (f16*)take((size_t)N_NODES * HC * 2);
  int*   counts= (int*)take((size_t)N_NODES * 4);
  int*   offs  = (int*)take((size_t)(N_NODES + 1) * 4);
  int*   cur   = (int*)take((size_t)N_NODES * 4);
  int*   eids  = (int*)take((size_t)N_EDGES * 4);

  hipMemsetAsync(counts, 0, N_NODES * 4, stream);
  count_edges<<<N_EDGES / 256, 256, 0, stream>>>(dst, counts);
  scan_offsets<<<1, 256, 0, stream>>>(counts, offs, cur);
  fill_csr<<<N_EDGES / 256, 256, 0, stream>>>(dst, cur, eids);

  cvt_f32_f16<<<(N_NODES * F_IN) / 1024, 256, 0, stream>>>(x, Xh, N_NODES * F_IN);

  // layer 1: Xh -> Xh (edge kernel writes after GEMM has consumed Xh; stream-ordered, safe)
  run_layer(Xh, Wl1, bl1, Wr1, br1, We1, att1, bias1, src, eattr,
            WT, XL, XR, offs, eids, Xh, stream);
  // layer 2: Xh -> H2h
  run_layer(Xh, Wl2, bl2, Wr2, br2, We2, att2, bias2, src, eattr,
            WT, XL, XR, offs, eids, H2h, stream);

  pool_kernel<<<dim3(NGRAPH, HC / 256), 256, 0, stream>>>(H2h, batch, out);
}